// Round 2
// baseline (438.681 us; speedup 1.0000x reference)
//
#include <hip/hip_runtime.h>
#include <math.h>

// Problem constants (from reference): B=64, S=4096, H=256.
namespace {
constexpr int kB = 64;
constexpr int kS = 4096;
constexpr int kH = 256;
constexpr int kChunks = 32;                           // chunks per batch row
constexpr int kChunkS = kS / kChunks;                 // 128 positions per block
constexpr int kWavesPerBlock = 4;                     // 256 threads
constexpr int kPosPerWave = kChunkS / kWavesPerBlock; // 32 positions per wave
constexpr int kBatch = 8;                             // positions per softmax step
constexpr int kNumBatch = kPosPerWave / kBatch;       // 4
constexpr int kPartStride = kH + 2;                   // acc[256] + m + l
constexpr float kLog2e = 1.4426950408889634f;
constexpr float kNegL2 = 1.4426950408889634e30f;      // 1e30 * log2(e)
}

// Full-wave (64-lane) sum via DPP — no LDS-pipe ops.
// row_shr 1/2/4/8 build row-of-16 prefix sums; row_bcast:15/31 merge rows;
// lane 63 holds the total, broadcast via readlane.
__device__ __forceinline__ float dpp_sum64(float x) {
  float f = x;
#define DPP_STEP(ctrl)                                                     \
  f += __int_as_float(__builtin_amdgcn_update_dpp(                         \
      0, __float_as_int(f), ctrl, 0xF, 0xF, true))
  DPP_STEP(0x111);  // row_shr:1
  DPP_STEP(0x112);  // row_shr:2
  DPP_STEP(0x114);  // row_shr:4
  DPP_STEP(0x118);  // row_shr:8
  DPP_STEP(0x142);  // row_bcast:15
  DPP_STEP(0x143);  // row_bcast:31
#undef DPP_STEP
  return __int_as_float(__builtin_amdgcn_readlane(__float_as_int(f), 63));
}

// Pass 1: flash-style online softmax-weighted sum over a chunk of S.
// One wave per 32 positions; 64 lanes x float4 = one 1KiB coalesced row.
// Softmax math kept in base-2 (score2 = score*log2e) so exp == v_exp_f32.
__global__ __launch_bounds__(256, 4) void pass1_kernel(
    const float* __restrict__ x, const float* __restrict__ mask,
    const float* __restrict__ q, float* __restrict__ part) {
  const int blk = blockIdx.x;
  const int b = blk >> 5;  // blk / kChunks
  const int c = blk & (kChunks - 1);
  const int tid = threadIdx.x;
  const int wave = tid >> 6;
  const int lane = tid & 63;

  const float4 q4 = *reinterpret_cast<const float4*>(q + b * kH + lane * 4);
  const int s_base = c * kChunkS + wave * kPosPerWave;
  const float* xw = x + ((size_t)b * kS + s_base) * kH + lane * 4;
  const float* mrow = mask + b * kS + s_base;

  float m = -INFINITY;  // running max in base-2 units
  float l = 0.f;
  float4 acc = make_float4(0.f, 0.f, 0.f, 0.f);

  #pragma unroll
  for (int i = 0; i < kNumBatch; ++i) {
    // Load 8 rows (8 KB per wave) + 8 mask values (uniform 16B loads).
    float4 xb[kBatch];
    #pragma unroll
    for (int j = 0; j < kBatch; ++j)
      xb[j] = *reinterpret_cast<const float4*>(xw + (i * kBatch + j) * kH);
    const float4 mk0 = *reinterpret_cast<const float4*>(mrow + i * kBatch);
    const float4 mk1 = *reinterpret_cast<const float4*>(mrow + i * kBatch + 4);
    const float bias[kBatch] = {
        (mk0.x - 1.f) * kNegL2, (mk0.y - 1.f) * kNegL2,
        (mk0.z - 1.f) * kNegL2, (mk0.w - 1.f) * kNegL2,
        (mk1.x - 1.f) * kNegL2, (mk1.y - 1.f) * kNegL2,
        (mk1.z - 1.f) * kNegL2, (mk1.w - 1.f) * kNegL2};

    // 8 scores via DPP reduction (pure VALU, no LDS).
    float s2[kBatch];
    #pragma unroll
    for (int j = 0; j < kBatch; ++j) {
      const float p = xb[j].x * q4.x + xb[j].y * q4.y +
                      xb[j].z * q4.z + xb[j].w * q4.w;
      s2[j] = fmaf(dpp_sum64(p), kLog2e, bias[j]);
    }

    // One online-softmax rescale per 8 positions.
    float M = s2[0];
    #pragma unroll
    for (int j = 1; j < kBatch; ++j) M = fmaxf(M, s2[j]);
    const float m_new = fmaxf(m, M);
    const float alpha = __builtin_amdgcn_exp2f(m - m_new);  // exp2(-inf)=0
    float w[kBatch];
    float wsum = 0.f;
    #pragma unroll
    for (int j = 0; j < kBatch; ++j) {
      w[j] = __builtin_amdgcn_exp2f(s2[j] - m_new);
      wsum += w[j];
    }
    l = fmaf(l, alpha, wsum);
    float ax = acc.x * alpha, ay = acc.y * alpha;
    float az = acc.z * alpha, aw = acc.w * alpha;
    #pragma unroll
    for (int j = 0; j < kBatch; ++j) {
      ax = fmaf(w[j], xb[j].x, ax);
      ay = fmaf(w[j], xb[j].y, ay);
      az = fmaf(w[j], xb[j].z, az);
      aw = fmaf(w[j], xb[j].w, aw);
    }
    acc = make_float4(ax, ay, az, aw);
    m = m_new;
  }

  // Combine the block's 4 waves in LDS (base-2 exponents).
  __shared__ float sm[kWavesPerBlock];
  __shared__ float sl[kWavesPerBlock];
  __shared__ float sacc[kWavesPerBlock][kH];
  if (lane == 0) { sm[wave] = m; sl[wave] = l; }
  *reinterpret_cast<float4*>(&sacc[wave][lane * 4]) = acc;
  __syncthreads();

  const float m_b = fmaxf(fmaxf(sm[0], sm[1]), fmaxf(sm[2], sm[3]));
  const float a0 = __builtin_amdgcn_exp2f(sm[0] - m_b);
  const float a1 = __builtin_amdgcn_exp2f(sm[1] - m_b);
  const float a2 = __builtin_amdgcn_exp2f(sm[2] - m_b);
  const float a3 = __builtin_amdgcn_exp2f(sm[3] - m_b);
  float* out = part + (size_t)blk * kPartStride;
  out[tid] = sacc[0][tid] * a0 + sacc[1][tid] * a1 +
             sacc[2][tid] * a2 + sacc[3][tid] * a3;
  if (tid == 0) {
    out[kH] = m_b;
    out[kH + 1] = sl[0] * a0 + sl[1] * a1 + sl[2] * a2 + sl[3] * a3;
  }
}

// Pass 2: per-batch combine of 32 partials + fused 512->256 linear epilogue.
__global__ __launch_bounds__(256, 4) void pass2_kernel(
    const float* __restrict__ part, const float* __restrict__ q,
    const float* __restrict__ W, const float* __restrict__ bias,
    float* __restrict__ out) {
  const int b = blockIdx.x;
  const int tid = threadIdx.x;

  const float* pb = part + (size_t)b * kChunks * kPartStride;
  float m_g = -INFINITY;
  #pragma unroll
  for (int c = 0; c < kChunks; ++c)
    m_g = fmaxf(m_g, pb[c * kPartStride + kH]);
  float l_g = 0.f, num = 0.f;
  #pragma unroll 4
  for (int c = 0; c < kChunks; ++c) {
    const float* p = pb + c * kPartStride;
    const float scale = __builtin_amdgcn_exp2f(p[kH] - m_g);
    l_g += scale * p[kH + 1];
    num += scale * p[tid];  // coalesced across the 256 threads
  }
  const float msg = num / l_g;
  out[(size_t)b * kH + tid] = msg;  // output 0: extracted_msg

  __shared__ float conc[2 * kH];
  conc[tid] = q[b * kH + tid];
  conc[kH + tid] = msg;
  __syncthreads();

  float acc = bias[tid];
  const float* wr = W + (size_t)tid * (2 * kH);  // row h = tid of W [H, 2H]
  #pragma unroll 8
  for (int j = 0; j < 2 * kH; j += 4) {
    const float4 w4 = *reinterpret_cast<const float4*>(wr + j);
    acc += conc[j] * w4.x + conc[j + 1] * w4.y +
           conc[j + 2] * w4.z + conc[j + 3] * w4.w;
  }
  out[(size_t)(kB * kH) + (size_t)b * kH + tid] = acc;  // output 1: control_emb
}

extern "C" void kernel_launch(void* const* d_in, const int* in_sizes, int n_in,
                              void* d_out, int out_size, void* d_ws, size_t ws_size,
                              hipStream_t stream) {
  const float* x    = (const float*)d_in[0];  // inp_seq [B,S,H]
  const float* mask = (const float*)d_in[1];  // [B,S]
  const float* q    = (const float*)d_in[2];  // [B,H]
  const float* W    = (const float*)d_in[3];  // [H,2H]
  const float* bias = (const float*)d_in[4];  // [H]
  float* out = (float*)d_out;                 // [B*H extracted_msg][B*H control_emb]
  float* part = (float*)d_ws;                 // B*kChunks*(H+2) floats = 2.1 MB

  pass1_kernel<<<kB * kChunks, 256, 0, stream>>>(x, mask, q, part);
  pass2_kernel<<<kB, 256, 0, stream>>>(part, q, W, bias, out);
}

// Round 3
// 430.313 us; speedup vs baseline: 1.0194x; 1.0194x over previous
//
#include <hip/hip_runtime.h>
#include <math.h>

// Problem constants (from reference): B=64, S=4096, H=256.
namespace {
constexpr int kB = 64;
constexpr int kS = 4096;
constexpr int kH = 256;
constexpr int kChunks = 32;                           // chunks per batch row
constexpr int kChunkS = kS / kChunks;                 // 128 positions per block
constexpr int kWavesPerBlock = 4;                     // 256 threads
constexpr int kPosPerWave = kChunkS / kWavesPerBlock; // 32 positions per wave
constexpr int kPartStride = kH + 2;                   // acc[256] + m + l
constexpr float kLog2e = 1.4426950408889634f;
constexpr float kNegL2 = 1.4426950408889634e30f;      // 1e30 * log2(e)
}

// Full-wave (64-lane) sum via DPP — no LDS-pipe ops.
__device__ __forceinline__ float dpp_sum64(float x) {
  float f = x;
#define DPP_STEP(ctrl)                                                     \
  f += __int_as_float(__builtin_amdgcn_update_dpp(                         \
      0, __float_as_int(f), ctrl, 0xF, 0xF, true))
  DPP_STEP(0x111);  // row_shr:1
  DPP_STEP(0x112);  // row_shr:2
  DPP_STEP(0x114);  // row_shr:4
  DPP_STEP(0x118);  // row_shr:8
  DPP_STEP(0x142);  // row_bcast:15
  DPP_STEP(0x143);  // row_bcast:31
#undef DPP_STEP
  return __int_as_float(__builtin_amdgcn_readlane(__float_as_int(f), 63));
}

__device__ __forceinline__ float dot4(const float4 a, const float4 b) {
  return fmaf(a.x, b.x, fmaf(a.y, b.y, fmaf(a.z, b.z, a.w * b.w)));
}

// Pass 1: flash-style online softmax-weighted sum over a chunk of S.
// One wave per 32 positions; 64 lanes x float4 = one 1KiB coalesced row.
// NO local arrays anywhere in the hot loop — named scalars only, so nothing
// can be demoted to scratch (round-2 spilled 241 MB of scratch writes).
__global__ __launch_bounds__(256, 4) void pass1_kernel(
    const float* __restrict__ x, const float* __restrict__ mask,
    const float* __restrict__ q, float* __restrict__ part) {
  const int blk = blockIdx.x;
  const int b = blk >> 5;  // blk / kChunks
  const int c = blk & (kChunks - 1);
  const int tid = threadIdx.x;
  const int wave = tid >> 6;
  const int lane = tid & 63;

  const float4 q4 = *reinterpret_cast<const float4*>(q + b * kH + lane * 4);
  const int s_base = c * kChunkS + wave * kPosPerWave;
  const float* xw = x + ((size_t)b * kS + s_base) * kH + lane * 4;
  const float* mrow = mask + b * kS + s_base;

  float m = -INFINITY;  // running max in base-2 units
  float l = 0.f;
  float ax = 0.f, ay = 0.f, az = 0.f, aw = 0.f;

  #pragma unroll
  for (int i = 0; i < kPosPerWave / 4; ++i) {  // 8 batches of 4 positions
    const float* p0 = xw + i * 4 * kH;
    const float4 x0 = *reinterpret_cast<const float4*>(p0);
    const float4 x1 = *reinterpret_cast<const float4*>(p0 + kH);
    const float4 x2 = *reinterpret_cast<const float4*>(p0 + 2 * kH);
    const float4 x3 = *reinterpret_cast<const float4*>(p0 + 3 * kH);
    const float4 mk = *reinterpret_cast<const float4*>(mrow + i * 4);  // uniform

    // 4 scores via DPP reduction (pure VALU, no LDS), base-2 units.
    const float s0 = fmaf(dpp_sum64(dot4(x0, q4)), kLog2e, (mk.x - 1.f) * kNegL2);
    const float s1 = fmaf(dpp_sum64(dot4(x1, q4)), kLog2e, (mk.y - 1.f) * kNegL2);
    const float s2 = fmaf(dpp_sum64(dot4(x2, q4)), kLog2e, (mk.z - 1.f) * kNegL2);
    const float s3 = fmaf(dpp_sum64(dot4(x3, q4)), kLog2e, (mk.w - 1.f) * kNegL2);

    // One online-softmax rescale per 4 positions.
    const float m_new = fmaxf(fmaxf(fmaxf(s0, s1), fmaxf(s2, s3)), m);
    const float alpha = __builtin_amdgcn_exp2f(m - m_new);  // exp2(-inf)=0
    const float w0 = __builtin_amdgcn_exp2f(s0 - m_new);
    const float w1 = __builtin_amdgcn_exp2f(s1 - m_new);
    const float w2 = __builtin_amdgcn_exp2f(s2 - m_new);
    const float w3 = __builtin_amdgcn_exp2f(s3 - m_new);
    l = fmaf(l, alpha, (w0 + w1) + (w2 + w3));
    ax = fmaf(w3, x3.x, fmaf(w2, x2.x, fmaf(w1, x1.x, fmaf(w0, x0.x, ax * alpha))));
    ay = fmaf(w3, x3.y, fmaf(w2, x2.y, fmaf(w1, x1.y, fmaf(w0, x0.y, ay * alpha))));
    az = fmaf(w3, x3.z, fmaf(w2, x2.z, fmaf(w1, x1.z, fmaf(w0, x0.z, az * alpha))));
    aw = fmaf(w3, x3.w, fmaf(w2, x2.w, fmaf(w1, x1.w, fmaf(w0, x0.w, aw * alpha))));
    m = m_new;
  }

  // Combine the block's 4 waves in LDS (base-2 exponents).
  __shared__ float sm[kWavesPerBlock];
  __shared__ float sl[kWavesPerBlock];
  __shared__ float sacc[kWavesPerBlock][kH];
  if (lane == 0) { sm[wave] = m; sl[wave] = l; }
  *reinterpret_cast<float4*>(&sacc[wave][lane * 4]) =
      make_float4(ax, ay, az, aw);
  __syncthreads();

  const float m_b = fmaxf(fmaxf(sm[0], sm[1]), fmaxf(sm[2], sm[3]));
  const float a0 = __builtin_amdgcn_exp2f(sm[0] - m_b);
  const float a1 = __builtin_amdgcn_exp2f(sm[1] - m_b);
  const float a2 = __builtin_amdgcn_exp2f(sm[2] - m_b);
  const float a3 = __builtin_amdgcn_exp2f(sm[3] - m_b);
  float* out = part + (size_t)blk * kPartStride;
  out[tid] = sacc[0][tid] * a0 + sacc[1][tid] * a1 +
             sacc[2][tid] * a2 + sacc[3][tid] * a3;
  if (tid == 0) {
    out[kH] = m_b;
    out[kH + 1] = sl[0] * a0 + sl[1] * a1 + sl[2] * a2 + sl[3] * a3;
  }
}

// Pass 2: per-batch combine of 32 partials + fused 512->256 linear epilogue.
__global__ __launch_bounds__(256, 4) void pass2_kernel(
    const float* __restrict__ part, const float* __restrict__ q,
    const float* __restrict__ W, const float* __restrict__ bias,
    float* __restrict__ out) {
  const int b = blockIdx.x;
  const int tid = threadIdx.x;

  const float* pb = part + (size_t)b * kChunks * kPartStride;
  float m_g = -INFINITY;
  #pragma unroll
  for (int c = 0; c < kChunks; ++c)
    m_g = fmaxf(m_g, pb[c * kPartStride + kH]);
  float l_g = 0.f, num = 0.f;
  #pragma unroll 4
  for (int c = 0; c < kChunks; ++c) {
    const float* p = pb + c * kPartStride;
    const float scale = __builtin_amdgcn_exp2f(p[kH] - m_g);
    l_g += scale * p[kH + 1];
    num += scale * p[tid];  // coalesced across the 256 threads
  }
  const float msg = num / l_g;
  out[(size_t)b * kH + tid] = msg;  // output 0: extracted_msg

  __shared__ float conc[2 * kH];
  conc[tid] = q[b * kH + tid];
  conc[kH + tid] = msg;
  __syncthreads();

  float acc = bias[tid];
  const float* wr = W + (size_t)tid * (2 * kH);  // row h = tid of W [H, 2H]
  #pragma unroll 8
  for (int j = 0; j < 2 * kH; j += 4) {
    const float4 w4 = *reinterpret_cast<const float4*>(wr + j);
    acc += conc[j] * w4.x + conc[j + 1] * w4.y +
           conc[j + 2] * w4.z + conc[j + 3] * w4.w;
  }
  out[(size_t)(kB * kH) + (size_t)b * kH + tid] = acc;  // output 1: control_emb
}

extern "C" void kernel_launch(void* const* d_in, const int* in_sizes, int n_in,
                              void* d_out, int out_size, void* d_ws, size_t ws_size,
                              hipStream_t stream) {
  const float* x    = (const float*)d_in[0];  // inp_seq [B,S,H]
  const float* mask = (const float*)d_in[1];  // [B,S]
  const float* q    = (const float*)d_in[2];  // [B,H]
  const float* W    = (const float*)d_in[3];  // [H,2H]
  const float* bias = (const float*)d_in[4];  // [H]
  float* out = (float*)d_out;                 // [B*H extracted_msg][B*H control_emb]
  float* part = (float*)d_ws;                 // B*kChunks*(H+2) floats = 2.1 MB

  pass1_kernel<<<kB * kChunks, 256, 0, stream>>>(x, mask, q, part);
  pass2_kernel<<<kB, 256, 0, stream>>>(part, q, W, bias, out);
}

// Round 4
// 352.699 us; speedup vs baseline: 1.2438x; 1.2201x over previous
//
#include <hip/hip_runtime.h>
#include <math.h>

// Problem constants (from reference): B=64, S=4096, H=256.
namespace {
constexpr int kB = 64;
constexpr int kS = 4096;
constexpr int kH = 256;
constexpr int kChunks = 32;                           // chunks per batch row
constexpr int kChunkS = kS / kChunks;                 // 128 positions per block
constexpr int kWavesPerBlock = 4;                     // 256 threads
constexpr int kPosPerWave = kChunkS / kWavesPerBlock; // 32 positions per wave
constexpr int kPartStride = kH + 2;                   // acc[256] + m + l
constexpr float kLog2e = 1.4426950408889634f;
}

// Full-wave (64-lane) sum via DPP — pure VALU, no LDS-pipe ops.
__device__ __forceinline__ float dpp_sum64(float x) {
  float f = x;
#define DPP_STEP(ctrl)                                                     \
  f += __int_as_float(__builtin_amdgcn_update_dpp(                         \
      0, __float_as_int(f), ctrl, 0xF, 0xF, true))
  DPP_STEP(0x111);  // row_shr:1
  DPP_STEP(0x112);  // row_shr:2
  DPP_STEP(0x114);  // row_shr:4
  DPP_STEP(0x118);  // row_shr:8
  DPP_STEP(0x142);  // row_bcast:15
  DPP_STEP(0x143);  // row_bcast:31
#undef DPP_STEP
  return __int_as_float(__builtin_amdgcn_readlane(__float_as_int(f), 63));
}

__device__ __forceinline__ float dot4(const float4 a, const float4 b) {
  return fmaf(a.x, b.x, fmaf(a.y, b.y, fmaf(a.z, b.z, a.w * b.w)));
}

// Pass 1: flash-style online softmax-weighted sum over a chunk of S.
// KEY: mask values are exactly {0,1}; mask==0 rows have softmax weight
// exactly 0 in fp32, so we SKIP them entirely — halves HBM traffic and is
// bit-equivalent. Valid rows iterated via a wave-uniform ballot bitmask with
// a 2-deep manual prefetch pipeline (loads issue before the reduce chain).
__global__ __launch_bounds__(256, 8) void pass1_kernel(
    const float* __restrict__ x, const float* __restrict__ mask,
    const float* __restrict__ q, float* __restrict__ part) {
  const int blk = blockIdx.x;
  const int b = blk >> 5;  // blk / kChunks
  const int c = blk & (kChunks - 1);
  const int tid = threadIdx.x;
  const int wave = tid >> 6;
  const int lane = tid & 63;

  const float4 q4 = *reinterpret_cast<const float4*>(q + b * kH + lane * 4);
  const int s_base = c * kChunkS + wave * kPosPerWave;
  const float* xw = x + ((size_t)b * kS + s_base) * kH + lane * 4;
  const float* mrow = mask + b * kS + s_base;

  // Wave-uniform bitmask of valid positions (bit i = mask[s_base+i] != 0).
  const float mv = mrow[lane & 31];
  unsigned long long vm = __ballot(mv != 0.f) & 0xffffffffull;

  float m = -INFINITY;  // running max in base-2 units
  float l = 0.f;
  float ax = 0.f, ay = 0.f, az = 0.f, aw = 0.f;

  auto loadrow = [&](int s) -> float4 {
    return *reinterpret_cast<const float4*>(xw + s * kH);
  };
  auto process = [&](const float4 xv) {
    const float s2 = dpp_sum64(dot4(xv, q4)) * kLog2e;
    const float m_new = fmaxf(m, s2);
    const float alpha = __builtin_amdgcn_exp2f(m - m_new);  // exp2(-inf)=0
    const float w = __builtin_amdgcn_exp2f(s2 - m_new);
    l = fmaf(l, alpha, w);
    ax = fmaf(w, xv.x, ax * alpha);
    ay = fmaf(w, xv.y, ay * alpha);
    az = fmaf(w, xv.z, az * alpha);
    aw = fmaf(w, xv.w, aw * alpha);
    m = m_new;
  };

  if (vm) {
    int s0 = __builtin_ctzll(vm);
    vm &= vm - 1;
    float4 x0 = loadrow(s0);
    if (vm) {
      int s1 = __builtin_ctzll(vm);
      vm &= vm - 1;
      float4 x1 = loadrow(s1);
      while (vm) {
        const int s2i = __builtin_ctzll(vm);
        vm &= vm - 1;
        const float4 x2 = loadrow(s2i);  // prefetch before touching x0
        process(x0);
        x0 = x1;
        x1 = x2;
      }
      process(x0);
      x0 = x1;
    }
    process(x0);
  }
  // Empty wave (all 32 masked): m=-inf, l=0, acc=0 — handled below.

  // Combine the block's 4 waves in LDS (base-2 exponents).
  __shared__ float sm[kWavesPerBlock];
  __shared__ float sl[kWavesPerBlock];
  __shared__ float sacc[kWavesPerBlock][kH];
  if (lane == 0) { sm[wave] = m; sl[wave] = l; }
  *reinterpret_cast<float4*>(&sacc[wave][lane * 4]) =
      make_float4(ax, ay, az, aw);
  __syncthreads();

  const float m_b = fmaxf(fmaxf(sm[0], sm[1]), fmaxf(sm[2], sm[3]));
  // Guard: if the whole chunk is masked, m_b=-inf; use 0 in the exponent
  // differences so a_i = exp2(-inf - 0) = 0 (avoids (-inf)-(-inf)=NaN).
  const float m_bs = (m_b == -INFINITY) ? 0.f : m_b;
  const float a0 = __builtin_amdgcn_exp2f(sm[0] - m_bs);
  const float a1 = __builtin_amdgcn_exp2f(sm[1] - m_bs);
  const float a2 = __builtin_amdgcn_exp2f(sm[2] - m_bs);
  const float a3 = __builtin_amdgcn_exp2f(sm[3] - m_bs);
  float* out = part + (size_t)blk * kPartStride;
  out[tid] = sacc[0][tid] * a0 + sacc[1][tid] * a1 +
             sacc[2][tid] * a2 + sacc[3][tid] * a3;
  if (tid == 0) {
    out[kH] = m_b;  // -inf for fully-masked chunk -> scale 0 in pass 2
    out[kH + 1] = sl[0] * a0 + sl[1] * a1 + sl[2] * a2 + sl[3] * a3;
  }
}

// Pass 2: per-batch combine of 32 partials + fused 512->256 linear epilogue.
__global__ __launch_bounds__(256, 4) void pass2_kernel(
    const float* __restrict__ part, const float* __restrict__ q,
    const float* __restrict__ W, const float* __restrict__ bias,
    float* __restrict__ out) {
  const int b = blockIdx.x;
  const int tid = threadIdx.x;

  const float* pb = part + (size_t)b * kChunks * kPartStride;
  float m_g = -INFINITY;  // finite: every row has >=1 valid position
  #pragma unroll
  for (int c = 0; c < kChunks; ++c)
    m_g = fmaxf(m_g, pb[c * kPartStride + kH]);
  float l_g = 0.f, num = 0.f;
  #pragma unroll 4
  for (int c = 0; c < kChunks; ++c) {
    const float* p = pb + c * kPartStride;
    const float scale = __builtin_amdgcn_exp2f(p[kH] - m_g);
    l_g += scale * p[kH + 1];
    num += scale * p[tid];  // coalesced across the 256 threads
  }
  const float msg = num / l_g;
  out[(size_t)b * kH + tid] = msg;  // output 0: extracted_msg

  __shared__ float conc[2 * kH];
  conc[tid] = q[b * kH + tid];
  conc[kH + tid] = msg;
  __syncthreads();

  float acc = bias[tid];
  const float* wr = W + (size_t)tid * (2 * kH);  // row h = tid of W [H, 2H]
  #pragma unroll 8
  for (int j = 0; j < 2 * kH; j += 4) {
    const float4 w4 = *reinterpret_cast<const float4*>(wr + j);
    acc += conc[j] * w4.x + conc[j + 1] * w4.y +
           conc[j + 2] * w4.z + conc[j + 3] * w4.w;
  }
  out[(size_t)(kB * kH) + (size_t)b * kH + tid] = acc;  // output 1: control_emb
}

extern "C" void kernel_launch(void* const* d_in, const int* in_sizes, int n_in,
                              void* d_out, int out_size, void* d_ws, size_t ws_size,
                              hipStream_t stream) {
  const float* x    = (const float*)d_in[0];  // inp_seq [B,S,H]
  const float* mask = (const float*)d_in[1];  // [B,S]
  const float* q    = (const float*)d_in[2];  // [B,H]
  const float* W    = (const float*)d_in[3];  // [H,2H]
  const float* bias = (const float*)d_in[4];  // [H]
  float* out = (float*)d_out;                 // [B*H extracted_msg][B*H control_emb]
  float* part = (float*)d_ws;                 // B*kChunks*(H+2) floats = 2.1 MB

  pass1_kernel<<<kB * kChunks, 256, 0, stream>>>(x, mask, q, part);
  pass2_kernel<<<kB, 256, 0, stream>>>(part, q, W, bias, out);
}